// Round 11
// baseline (506.222 us; speedup 1.0000x reference)
//
#include <hip/hip_runtime.h>
#include <hip/hip_bf16.h>

// GraphMatchingLayer, round 11: round-10 structure; edge kernel inner loop
// rebuilt ("free the loop"):
//   1. W1c column held as 16 pinned v2f (asm "+v" -> cannot remat/reload)
//   2. v_pk_fma_f32 via __builtin_elementwise_fma on float2 (16 vs 32 FMA)
//   3. NO fences: wave-private strip + same-wave LDS ops are in-order at the
//      banks; compiler's alias-driven waits handle reg dependencies. Scheduler
//      may now pipeline next-chunk loads under current-chunk FMAs.

#define TPB 256

typedef float v2f __attribute__((ext_vector_type(2)));
typedef float v4f __attribute__((ext_vector_type(4)));

// 32-wide dense segment (weights via wave-uniform address -> scalar loads)
#define SEG32(SRC, NCH, KB, W, COL, ACC)                                \
  for (int kc_ = 0; kc_ < (NCH); ++kc_) {                               \
    const float4 a_ = ((const float4*)(SRC))[kc_];                      \
    const float av_[4] = {a_.x, a_.y, a_.z, a_.w};                      \
    _Pragma("unroll")                                                   \
    for (int j_ = 0; j_ < 4; ++j_) {                                    \
      const float ak_ = av_[j_];                                        \
      const float* wr_ = (W) + ((KB) + kc_ * 4 + j_) * 64 + (COL);      \
      _Pragma("unroll")                                                 \
      for (int cc_ = 0; cc_ < 32; ++cc_)                                \
        ACC[cc_] = fmaf(ak_, wr_[cc_], ACC[cc_]);                       \
    }                                                                   \
  }

// ---------------- CSR build ----------------

__global__ __launch_bounds__(TPB)
void k_hist(const int* __restrict__ ei, int* __restrict__ deg, int E) {
  int e = blockIdx.x * TPB + threadIdx.x;
  if (e < E) atomicAdd(&deg[ei[e]], 1);
}

__global__ __launch_bounds__(TPB)
void k_red(const int* __restrict__ deg, int* __restrict__ bsum, int N) {
  __shared__ int s[TPB];
  const int tid = threadIdx.x;
  const int g = (blockIdx.x * TPB + tid) * 4;
  int v = 0;
  #pragma unroll
  for (int j = 0; j < 4; ++j) if (g + j < N) v += deg[g + j];
  s[tid] = v;
  __syncthreads();
  for (int off = TPB / 2; off > 0; off >>= 1) {
    if (tid < off) s[tid] += s[tid + off];
    __syncthreads();
  }
  if (tid == 0) bsum[blockIdx.x] = s[0];
}

__global__ __launch_bounds__(TPB)
void k_apply2(const int* __restrict__ deg, const int* __restrict__ bsum,
              int* __restrict__ cur, int N) {
  __shared__ int s[TPB];
  __shared__ int sbase;
  const int tid = threadIdx.x;
  const int g = (blockIdx.x * TPB + tid) * 4;

  if (tid < 64) {
    int v = 0;
    for (int i = tid; i < (int)blockIdx.x; i += 64) v += bsum[i];
    #pragma unroll
    for (int off = 32; off > 0; off >>= 1) v += __shfl_down(v, off);
    if (tid == 0) sbase = v;
  }

  int d[4];
  int v = 0;
  #pragma unroll
  for (int j = 0; j < 4; ++j) { d[j] = (g + j < N) ? deg[g + j] : 0; v += d[j]; }
  s[tid] = v;
  __syncthreads();
  for (int off = 1; off < TPB; off <<= 1) {
    int t = (tid >= off) ? s[tid - off] : 0;
    __syncthreads();
    s[tid] += t;
    __syncthreads();
  }
  int base = sbase + s[tid] - v;
  #pragma unroll
  for (int j = 0; j < 4; ++j)
    if (g + j < N) { cur[g + j] = base; base += d[j]; }
}

__global__ __launch_bounds__(TPB)
void k_scatter(const int* __restrict__ ei, int* __restrict__ cur,
               int2* __restrict__ ec, int E) {
  int e = blockIdx.x * TPB + threadIdx.x;
  if (e < E) {
    const int r = ei[e];
    const int c = ei[E + e];
    int p = atomicAdd(&cur[r], 1);
    ec[p] = make_int2(e, c);
  }
}

// ---------------- U/V precompute: 4-way wave split ----------------

__global__ __launch_bounds__(TPB)
void k_prep3(const float* __restrict__ x,
             const float* __restrict__ ew1, const float* __restrict__ eb1,
             float* __restrict__ U, float* __restrict__ V, int N)
{
  const int t = blockIdx.x * TPB + threadIdx.x;
  const int wv = __builtin_amdgcn_readfirstlane(t >> 6);
  const int lane = t & 63;
  const int q = wv & 3;
  const int n = (wv >> 2) * 64 + lane;
  if (n >= N) return;

  const int uv = q >> 1;
  const int h = (q & 1) * 32;
  const float* W = ew1 + uv * 64 * 64;

  float acc[32];
  if (uv) {
    #pragma unroll
    for (int j = 0; j < 32; ++j) acc[j] = 0.f;
  } else {
    #pragma unroll
    for (int j = 0; j < 32; ++j) acc[j] = eb1[h + j];
  }
  SEG32(x + (size_t)n * 64, 16, 0, W, h, acc)

  float* dst = (uv ? V : U) + (size_t)n * 64 + h;
  float4* d4 = (float4*)dst;
  #pragma unroll
  for (int c4 = 0; c4 < 8; ++c4)
    d4[c4] = make_float4(acc[c4*4+0], acc[c4*4+1], acc[c4*4+2], acc[c4*4+3]);
}

// ---------------- edge phase: wave/node, pk_fma, pinned weights ----------------

__global__ __launch_bounds__(TPB, 4)
void k_edge8(const float* __restrict__ U, const float* __restrict__ V,
             const float* __restrict__ ea,
             const float* __restrict__ ew1,
             const int* __restrict__ deg, const int* __restrict__ cur,
             const int2* __restrict__ ec,
             float* __restrict__ H, int N)
{
  __shared__ float sbuf[4 * 256];

  const int lane = threadIdx.x & 63;
  const int wid  = __builtin_amdgcn_readfirstlane(threadIdx.x >> 6);
  const int n    = __builtin_amdgcn_readfirstlane((int)blockIdx.x * 4 + wid);
  if (n >= N) return;

  const int d  = __builtin_amdgcn_readfirstlane(deg[n]);
  const int s0 = __builtin_amdgcn_readfirstlane(cur[n]) - d;

  float* lw = sbuf + wid * 256;
  const int g = lane >> 3;
  const int o = lane & 7;

  // this lane's W1c column as 16 pinned float2 (v_pk_fma operands)
  const float* wcol = ew1 + 128 * 64 + lane;
  v2f w2[16];
  #pragma unroll
  for (int i = 0; i < 16; ++i) {
    w2[i].x = wcol[(2 * i) * 64];
    w2[i].y = wcol[(2 * i + 1) * 64];
  }
  asm volatile("" : "+v"(w2[0]), "+v"(w2[1]), "+v"(w2[2]), "+v"(w2[3]),
                    "+v"(w2[4]), "+v"(w2[5]), "+v"(w2[6]), "+v"(w2[7]),
                    "+v"(w2[8]), "+v"(w2[9]), "+v"(w2[10]), "+v"(w2[11]),
                    "+v"(w2[12]), "+v"(w2[13]), "+v"(w2[14]), "+v"(w2[15]));

  const float u = U[(size_t)n * 64 + lane];
  const int2* ecp = ec + s0;
  float acc = 0.f;

  for (int i = 0; i < d; i += 8) {
    const int rem = d - i;
    const int gg = (g < rem) ? g : rem - 1;

    const int2 ecv = ecp[i + gg];
    const float4 eav = *(const float4*)(ea + (size_t)ecv.x * 32 + o * 4);

    const int c0 = __builtin_amdgcn_readlane(ecv.y, 0);
    const int c1 = __builtin_amdgcn_readlane(ecv.y, 8);
    const int c2 = __builtin_amdgcn_readlane(ecv.y, 16);
    const int c3 = __builtin_amdgcn_readlane(ecv.y, 24);
    const int c4 = __builtin_amdgcn_readlane(ecv.y, 32);
    const int c5 = __builtin_amdgcn_readlane(ecv.y, 40);
    const int c6 = __builtin_amdgcn_readlane(ecv.y, 48);
    const int c7 = __builtin_amdgcn_readlane(ecv.y, 56);
    const float v0 = V[(size_t)c0 * 64 + lane];
    const float v1 = V[(size_t)c1 * 64 + lane];
    const float v2 = V[(size_t)c2 * 64 + lane];
    const float v3 = V[(size_t)c3 * 64 + lane];
    const float v4 = V[(size_t)c4 * 64 + lane];
    const float v5 = V[(size_t)c5 * 64 + lane];
    const float v6 = V[(size_t)c6 * 64 + lane];
    const float v7 = V[(size_t)c7 * 64 + lane];

    // wave-private strip; same-wave LDS ops are in-order at the banks, and
    // the compiler's alias-driven s_waitcnt handles register dependencies.
    *(float4*)(lw + lane * 4) = eav;

    const float vs[8] = {v0, v1, v2, v3, v4, v5, v6, v7};
    #pragma unroll
    for (int j = 0; j < 8; ++j) {
      const float* er = lw + j * 32;      // uniform addr -> broadcast reads
      v2f t0 = {u, 0.f}, t1 = {0.f, 0.f}, t2 = {0.f, 0.f}, t3 = {0.f, 0.f};
      #pragma unroll
      for (int kq = 0; kq < 8; kq += 2) {
        const v4f qa = *(const v4f*)(er + kq * 4);
        const v4f qb = *(const v4f*)(er + kq * 4 + 4);
        t0 = __builtin_elementwise_fma(qa.lo, w2[2 * kq],     t0);
        t1 = __builtin_elementwise_fma(qa.hi, w2[2 * kq + 1], t1);
        t2 = __builtin_elementwise_fma(qb.lo, w2[2 * kq + 2], t2);
        t3 = __builtin_elementwise_fma(qb.hi, w2[2 * kq + 3], t3);
      }
      const v2f s2 = (t0 + t1) + (t2 + t3);
      const float s = fmaxf(s2.x + s2.y + vs[j], 0.f);
      acc += (j < rem) ? s : 0.f;
    }
  }

  H[(size_t)n * 64 + lane] = acc;
}

// ---------------- node MLP: two half-waves per node group ----------------

__global__ __launch_bounds__(TPB)
void k_node3(const float* __restrict__ x, const float* __restrict__ Hin,
             const int* __restrict__ deg,
             const float* __restrict__ ew2, const float* __restrict__ eb2,
             const float* __restrict__ nw1, const float* __restrict__ nb1,
             const float* __restrict__ nw2, const float* __restrict__ nb2,
             float* __restrict__ out, int N)
{
  __shared__ float sb[2][64 * 65];

  const int tid  = threadIdx.x;
  const int wv   = __builtin_amdgcn_readfirstlane(tid >> 6);
  const int lane = tid & 63;
  const int grp  = wv >> 1;
  const int h    = (wv & 1) * 32;

  const int n  = blockIdx.x * 128 + grp * 64 + lane;
  const bool valid = (n < N);
  const int nn = valid ? n : (N - 1);

  float* srow = &sb[grp][lane * 65];

  float acc[32];
  const float dg = (float)deg[nn];
  #pragma unroll
  for (int j = 0; j < 32; ++j) acc[j] = dg * eb2[h + j];
  SEG32(Hin + (size_t)nn * 64, 16, 0, ew2, h, acc)

  #pragma unroll
  for (int j = 0; j < 32; ++j) srow[h + j] = acc[j];
  __syncthreads();

  float bcc[32];
  #pragma unroll
  for (int j = 0; j < 32; ++j) bcc[j] = nb1[h + j];
  SEG32(x + (size_t)nn * 64, 16, 0, nw1, h, bcc)
  for (int k = 0; k < 64; ++k) {
    const float ak = srow[k];
    const float* wr = nw1 + (64 + k) * 64 + h;
    #pragma unroll
    for (int cc = 0; cc < 32; ++cc) bcc[cc] = fmaf(ak, wr[cc], bcc[cc]);
  }
  __syncthreads();

  #pragma unroll
  for (int j = 0; j < 32; ++j) srow[h + j] = fmaxf(bcc[j], 0.f);
  __syncthreads();

  float occ[32];
  #pragma unroll
  for (int j = 0; j < 32; ++j) occ[j] = nb2[h + j];
  for (int k = 0; k < 64; ++k) {
    const float ak = srow[k];
    const float* wr = nw2 + k * 64 + h;
    #pragma unroll
    for (int cc = 0; cc < 32; ++cc) occ[cc] = fmaf(ak, wr[cc], occ[cc]);
  }

  if (valid) {
    float4* ov = (float4*)(out + (size_t)n * 64 + h);
    #pragma unroll
    for (int c4 = 0; c4 < 8; ++c4)
      ov[c4] = make_float4(occ[c4*4+0], occ[c4*4+1], occ[c4*4+2], occ[c4*4+3]);
  }
}

// ---------------- launch ----------------

extern "C" void kernel_launch(void* const* d_in, const int* in_sizes, int n_in,
                              void* d_out, int out_size, void* d_ws, size_t ws_size,
                              hipStream_t stream) {
  const float* x   = (const float*)d_in[0];
  const int*   ei  = (const int*)d_in[1];
  const float* ea  = (const float*)d_in[2];
  const float* ew1 = (const float*)d_in[3];
  const float* eb1 = (const float*)d_in[4];
  const float* ew2 = (const float*)d_in[5];
  const float* eb2 = (const float*)d_in[6];
  const float* nw1 = (const float*)d_in[7];
  const float* nb1 = (const float*)d_in[8];
  const float* nw2 = (const float*)d_in[9];
  const float* nb2 = (const float*)d_in[10];
  float* out = (float*)d_out;

  const int N = in_sizes[0] / 64;   // 100000
  const int E = in_sizes[1] / 2;    // 1600000

  float* U   = (float*)d_ws;
  float* V   = U + (size_t)N * 64;
  int* ib    = (int*)(V + (size_t)N * 64);
  int* deg   = ib;
  int* cur   = ib + N;
  int* bsum  = ib + 2 * N;
  int2* ec   = (int2*)(ib + 2 * N + 1024);
  float* H   = out;

  const int NT = (N + 3) / 4;
  const int NB = (NT + TPB - 1) / TPB;

  hipMemsetAsync(deg, 0, (size_t)N * sizeof(int), stream);

  k_hist<<<(E + TPB - 1) / TPB, TPB, 0, stream>>>(ei, deg, E);
  k_red<<<NB, TPB, 0, stream>>>(deg, bsum, N);
  k_apply2<<<NB, TPB, 0, stream>>>(deg, bsum, cur, N);
  k_scatter<<<(E + TPB - 1) / TPB, TPB, 0, stream>>>(ei, cur, ec, E);

  {
    const int nwaves = 4 * ((N + 63) / 64);
    const int nblocks = (nwaves + 3) / 4;
    k_prep3<<<nblocks, TPB, 0, stream>>>(x, ew1, eb1, U, V, N);
  }

  k_edge8<<<(N + 3) / 4, TPB, 0, stream>>>(
      U, V, ea, ew1, deg, cur, ec, H, N);

  k_node3<<<(N + 127) / 128, TPB, 0, stream>>>(
      x, H, deg, ew2, eb2, nw1, nb1, nw2, nb2, out, N);
}

// Round 12
// 496.573 us; speedup vs baseline: 1.0194x; 1.0194x over previous
//
#include <hip/hip_runtime.h>
#include <hip/hip_bf16.h>

// GraphMatchingLayer, round 12: GRID-STRIDE / persistent blocks everywhere.
// r11 diagnosis: workgroup-launch-rate starvation (25K tiny blocks, ~7us
// wave lifetimes -> occupancy 37%). Fix: 2048-block persistent edge kernel
// (32 waves/CU resident), grid-stride hist/scatter/prep/node. Edge inner
// loop = r11 pk_fma + pinned w2 (per-wave load now amortized over ~12 nodes).

#define TPB 256
#define EDGE_BLOCKS 2048
#define SCAT_BLOCKS 2048
#define PREP_BLOCKS 1024
#define NODE_BLOCKS 1024

typedef float v2f __attribute__((ext_vector_type(2)));
typedef float v4f __attribute__((ext_vector_type(4)));

// 32-wide dense segment (weights via wave-uniform address -> scalar loads)
#define SEG32(SRC, NCH, KB, W, COL, ACC)                                \
  for (int kc_ = 0; kc_ < (NCH); ++kc_) {                               \
    const float4 a_ = ((const float4*)(SRC))[kc_];                      \
    const float av_[4] = {a_.x, a_.y, a_.z, a_.w};                      \
    _Pragma("unroll")                                                   \
    for (int j_ = 0; j_ < 4; ++j_) {                                    \
      const float ak_ = av_[j_];                                        \
      const float* wr_ = (W) + ((KB) + kc_ * 4 + j_) * 64 + (COL);      \
      _Pragma("unroll")                                                 \
      for (int cc_ = 0; cc_ < 32; ++cc_)                                \
        ACC[cc_] = fmaf(ak_, wr_[cc_], ACC[cc_]);                       \
    }                                                                   \
  }

// ---------------- CSR build (grid-stride) ----------------

__global__ __launch_bounds__(TPB)
void k_hist(const int* __restrict__ ei, int* __restrict__ deg, int E) {
  const int stride = gridDim.x * TPB;
  for (int e = blockIdx.x * TPB + threadIdx.x; e < E; e += stride)
    atomicAdd(&deg[ei[e]], 1);
}

__global__ __launch_bounds__(TPB)
void k_red(const int* __restrict__ deg, int* __restrict__ bsum, int N) {
  __shared__ int s[TPB];
  const int tid = threadIdx.x;
  const int g = (blockIdx.x * TPB + tid) * 4;
  int v = 0;
  #pragma unroll
  for (int j = 0; j < 4; ++j) if (g + j < N) v += deg[g + j];
  s[tid] = v;
  __syncthreads();
  for (int off = TPB / 2; off > 0; off >>= 1) {
    if (tid < off) s[tid] += s[tid + off];
    __syncthreads();
  }
  if (tid == 0) bsum[blockIdx.x] = s[0];
}

__global__ __launch_bounds__(TPB)
void k_apply2(const int* __restrict__ deg, const int* __restrict__ bsum,
              int* __restrict__ cur, int N) {
  __shared__ int s[TPB];
  __shared__ int sbase;
  const int tid = threadIdx.x;
  const int g = (blockIdx.x * TPB + tid) * 4;

  if (tid < 64) {
    int v = 0;
    for (int i = tid; i < (int)blockIdx.x; i += 64) v += bsum[i];
    #pragma unroll
    for (int off = 32; off > 0; off >>= 1) v += __shfl_down(v, off);
    if (tid == 0) sbase = v;
  }

  int d[4];
  int v = 0;
  #pragma unroll
  for (int j = 0; j < 4; ++j) { d[j] = (g + j < N) ? deg[g + j] : 0; v += d[j]; }
  s[tid] = v;
  __syncthreads();
  for (int off = 1; off < TPB; off <<= 1) {
    int t = (tid >= off) ? s[tid - off] : 0;
    __syncthreads();
    s[tid] += t;
    __syncthreads();
  }
  int base = sbase + s[tid] - v;
  #pragma unroll
  for (int j = 0; j < 4; ++j)
    if (g + j < N) { cur[g + j] = base; base += d[j]; }
}

__global__ __launch_bounds__(TPB)
void k_scatter(const int* __restrict__ ei, int* __restrict__ cur,
               int2* __restrict__ ec, int E) {
  const int stride = gridDim.x * TPB;
  for (int e = blockIdx.x * TPB + threadIdx.x; e < E; e += stride) {
    const int r = ei[e];
    const int c = ei[E + e];
    int p = atomicAdd(&cur[r], 1);
    ec[p] = make_int2(e, c);
  }
}

// ---------------- U/V precompute (grid-stride wave units) ----------------

__global__ __launch_bounds__(TPB)
void k_prep4(const float* __restrict__ x,
             const float* __restrict__ ew1, const float* __restrict__ eb1,
             float* __restrict__ U, float* __restrict__ V, int N)
{
  const int lane = threadIdx.x & 63;
  const int wid  = __builtin_amdgcn_readfirstlane(threadIdx.x >> 6);
  const int nunits = 4 * ((N + 63) / 64);
  const int wstride = gridDim.x * 4;

  for (int unit = blockIdx.x * 4 + wid; unit < nunits; unit += wstride) {
    const int q = unit & 3;
    const int n = (unit >> 2) * 64 + lane;
    if (n >= N) continue;

    const int uv = q >> 1;
    const int h = (q & 1) * 32;
    const float* W = ew1 + uv * 64 * 64;

    float acc[32];
    if (uv) {
      #pragma unroll
      for (int j = 0; j < 32; ++j) acc[j] = 0.f;
    } else {
      #pragma unroll
      for (int j = 0; j < 32; ++j) acc[j] = eb1[h + j];
    }
    SEG32(x + (size_t)n * 64, 16, 0, W, h, acc)

    float* dst = (uv ? V : U) + (size_t)n * 64 + h;
    float4* d4 = (float4*)dst;
    #pragma unroll
    for (int c4 = 0; c4 < 8; ++c4)
      d4[c4] = make_float4(acc[c4*4+0], acc[c4*4+1], acc[c4*4+2], acc[c4*4+3]);
  }
}

// ---------------- edge phase: persistent waves, pk_fma, pinned weights ----------------

__global__ __launch_bounds__(TPB, 4)
void k_edge9(const float* __restrict__ U, const float* __restrict__ V,
             const float* __restrict__ ea,
             const float* __restrict__ ew1,
             const int* __restrict__ deg, const int* __restrict__ cur,
             const int2* __restrict__ ec,
             float* __restrict__ H, int N)
{
  __shared__ float sbuf[4 * 256];

  const int lane = threadIdx.x & 63;
  const int wid  = __builtin_amdgcn_readfirstlane(threadIdx.x >> 6);

  float* lw = sbuf + wid * 256;
  const int g = lane >> 3;
  const int o = lane & 7;

  // this lane's W1c column as 16 pinned float2 — loaded ONCE per wave
  const float* wcol = ew1 + 128 * 64 + lane;
  v2f w2[16];
  #pragma unroll
  for (int i = 0; i < 16; ++i) {
    w2[i].x = wcol[(2 * i) * 64];
    w2[i].y = wcol[(2 * i + 1) * 64];
  }
  asm volatile("" : "+v"(w2[0]), "+v"(w2[1]), "+v"(w2[2]), "+v"(w2[3]),
                    "+v"(w2[4]), "+v"(w2[5]), "+v"(w2[6]), "+v"(w2[7]),
                    "+v"(w2[8]), "+v"(w2[9]), "+v"(w2[10]), "+v"(w2[11]),
                    "+v"(w2[12]), "+v"(w2[13]), "+v"(w2[14]), "+v"(w2[15]));

  const int wstride = gridDim.x * 4;

  for (int n = blockIdx.x * 4 + wid; n < N; n += wstride) {
    const int d  = __builtin_amdgcn_readfirstlane(deg[n]);
    const int s0 = __builtin_amdgcn_readfirstlane(cur[n]) - d;

    const float u = U[(size_t)n * 64 + lane];
    const int2* ecp = ec + s0;
    float acc = 0.f;

    for (int i = 0; i < d; i += 8) {
      const int rem = d - i;
      const int gg = (g < rem) ? g : rem - 1;

      const int2 ecv = ecp[i + gg];
      const float4 eav = *(const float4*)(ea + (size_t)ecv.x * 32 + o * 4);

      const int c0 = __builtin_amdgcn_readlane(ecv.y, 0);
      const int c1 = __builtin_amdgcn_readlane(ecv.y, 8);
      const int c2 = __builtin_amdgcn_readlane(ecv.y, 16);
      const int c3 = __builtin_amdgcn_readlane(ecv.y, 24);
      const int c4 = __builtin_amdgcn_readlane(ecv.y, 32);
      const int c5 = __builtin_amdgcn_readlane(ecv.y, 40);
      const int c6 = __builtin_amdgcn_readlane(ecv.y, 48);
      const int c7 = __builtin_amdgcn_readlane(ecv.y, 56);
      const float v0 = V[(size_t)c0 * 64 + lane];
      const float v1 = V[(size_t)c1 * 64 + lane];
      const float v2 = V[(size_t)c2 * 64 + lane];
      const float v3 = V[(size_t)c3 * 64 + lane];
      const float v4 = V[(size_t)c4 * 64 + lane];
      const float v5 = V[(size_t)c5 * 64 + lane];
      const float v6 = V[(size_t)c6 * 64 + lane];
      const float v7 = V[(size_t)c7 * 64 + lane];

      // wave-private strip; same-wave LDS ops are in-order at the banks
      *(float4*)(lw + lane * 4) = eav;

      const float vs[8] = {v0, v1, v2, v3, v4, v5, v6, v7};
      #pragma unroll
      for (int j = 0; j < 8; ++j) {
        const float* er = lw + j * 32;    // uniform addr -> broadcast reads
        v2f t0 = {u, 0.f}, t1 = {0.f, 0.f}, t2 = {0.f, 0.f}, t3 = {0.f, 0.f};
        #pragma unroll
        for (int kq = 0; kq < 8; kq += 2) {
          const v4f qa = *(const v4f*)(er + kq * 4);
          const v4f qb = *(const v4f*)(er + kq * 4 + 4);
          t0 = __builtin_elementwise_fma(qa.lo, w2[2 * kq],     t0);
          t1 = __builtin_elementwise_fma(qa.hi, w2[2 * kq + 1], t1);
          t2 = __builtin_elementwise_fma(qb.lo, w2[2 * kq + 2], t2);
          t3 = __builtin_elementwise_fma(qb.hi, w2[2 * kq + 3], t3);
        }
        const v2f s2 = (t0 + t1) + (t2 + t3);
        const float s = fmaxf(s2.x + s2.y + vs[j], 0.f);
        acc += (j < rem) ? s : 0.f;
      }
    }

    H[(size_t)n * 64 + lane] = acc;
  }
}

// ---------------- node MLP (grid-stride; r8 two-half-wave structure) ----------------

__global__ __launch_bounds__(TPB)
void k_node4(const float* __restrict__ x, const float* __restrict__ Hin,
             const int* __restrict__ deg,
             const float* __restrict__ ew2, const float* __restrict__ eb2,
             const float* __restrict__ nw1, const float* __restrict__ nb1,
             const float* __restrict__ nw2, const float* __restrict__ nb2,
             float* __restrict__ out, int N)
{
  __shared__ float sb[2][64 * 65];

  const int tid  = threadIdx.x;
  const int wv   = __builtin_amdgcn_readfirstlane(tid >> 6);
  const int lane = tid & 63;
  const int grp  = wv >> 1;
  const int h    = (wv & 1) * 32;

  for (int base = blockIdx.x * 128; base < N; base += gridDim.x * 128) {
    const int n  = base + grp * 64 + lane;
    const bool valid = (n < N);
    const int nn = valid ? n : (N - 1);

    float* srow = &sb[grp][lane * 65];

    float acc[32];
    const float dg = (float)deg[nn];
    #pragma unroll
    for (int j = 0; j < 32; ++j) acc[j] = dg * eb2[h + j];
    SEG32(Hin + (size_t)nn * 64, 16, 0, ew2, h, acc)

    #pragma unroll
    for (int j = 0; j < 32; ++j) srow[h + j] = acc[j];
    __syncthreads();

    float bcc[32];
    #pragma unroll
    for (int j = 0; j < 32; ++j) bcc[j] = nb1[h + j];
    SEG32(x + (size_t)nn * 64, 16, 0, nw1, h, bcc)
    for (int k = 0; k < 64; ++k) {
      const float ak = srow[k];
      const float* wr = nw1 + (64 + k) * 64 + h;
      #pragma unroll
      for (int cc = 0; cc < 32; ++cc) bcc[cc] = fmaf(ak, wr[cc], bcc[cc]);
    }
    __syncthreads();

    #pragma unroll
    for (int j = 0; j < 32; ++j) srow[h + j] = fmaxf(bcc[j], 0.f);
    __syncthreads();

    float occ[32];
    #pragma unroll
    for (int j = 0; j < 32; ++j) occ[j] = nb2[h + j];
    for (int k = 0; k < 64; ++k) {
      const float ak = srow[k];
      const float* wr = nw2 + k * 64 + h;
      #pragma unroll
      for (int cc = 0; cc < 32; ++cc) occ[cc] = fmaf(ak, wr[cc], occ[cc]);
    }

    if (valid) {
      float4* ov = (float4*)(out + (size_t)n * 64 + h);
      #pragma unroll
      for (int c4 = 0; c4 < 8; ++c4)
        ov[c4] = make_float4(occ[c4*4+0], occ[c4*4+1], occ[c4*4+2], occ[c4*4+3]);
    }
    __syncthreads();   // sb reuse safe across iterations
  }
}

// ---------------- launch ----------------

extern "C" void kernel_launch(void* const* d_in, const int* in_sizes, int n_in,
                              void* d_out, int out_size, void* d_ws, size_t ws_size,
                              hipStream_t stream) {
  const float* x   = (const float*)d_in[0];
  const int*   ei  = (const int*)d_in[1];
  const float* ea  = (const float*)d_in[2];
  const float* ew1 = (const float*)d_in[3];
  const float* eb1 = (const float*)d_in[4];
  const float* ew2 = (const float*)d_in[5];
  const float* eb2 = (const float*)d_in[6];
  const float* nw1 = (const float*)d_in[7];
  const float* nb1 = (const float*)d_in[8];
  const float* nw2 = (const float*)d_in[9];
  const float* nb2 = (const float*)d_in[10];
  float* out = (float*)d_out;

  const int N = in_sizes[0] / 64;   // 100000
  const int E = in_sizes[1] / 2;    // 1600000

  float* U   = (float*)d_ws;
  float* V   = U + (size_t)N * 64;
  int* ib    = (int*)(V + (size_t)N * 64);
  int* deg   = ib;
  int* cur   = ib + N;
  int* bsum  = ib + 2 * N;
  int2* ec   = (int2*)(ib + 2 * N + 1024);
  float* H   = out;

  const int NT = (N + 3) / 4;
  const int NB = (NT + TPB - 1) / TPB;            // 98

  hipMemsetAsync(deg, 0, (size_t)N * sizeof(int), stream);

  k_hist<<<SCAT_BLOCKS, TPB, 0, stream>>>(ei, deg, E);
  k_red<<<NB, TPB, 0, stream>>>(deg, bsum, N);
  k_apply2<<<NB, TPB, 0, stream>>>(deg, bsum, cur, N);
  k_scatter<<<SCAT_BLOCKS, TPB, 0, stream>>>(ei, cur, ec, E);

  k_prep4<<<PREP_BLOCKS, TPB, 0, stream>>>(x, ew1, eb1, U, V, N);

  k_edge9<<<EDGE_BLOCKS, TPB, 0, stream>>>(
      U, V, ea, ew1, deg, cur, ec, H, N);

  k_node4<<<NODE_BLOCKS, TPB, 0, stream>>>(
      x, H, deg, ew2, eb2, nw1, nb1, nw2, nb2, out, N);
}